// Round 6
// baseline (72.148 us; speedup 1.0000x reference)
//
#include <hip/hip_runtime.h>
#include <hip/hip_bf16.h>

// Problem constants
#define BB 8
#define L1 64
#define LL 1024
#define DD 512   // DIM_IN == DIM_H == DIM_M == 512

typedef float f32x4 __attribute__((ext_vector_type(4)));
typedef _Float16 f16;
typedef _Float16 f16x2 __attribute__((ext_vector_type(2)));
typedef _Float16 f16x4 __attribute__((ext_vector_type(4)));
typedef _Float16 f16x8 __attribute__((ext_vector_type(8)));

union F16x8u { f16x8 v; f16x2 h[4]; };

// ---------------------------------------------------------------------------
// K1: fused kx + qh GEMM via f16 MFMA 16x16x32.
// blockIdx.x in [0,64): kx[row,m] = keys @ Wx^T   (128x128 tile)
// blockIdx.x == 64:     qh[q,m]  = query @ Wh^T + bh  (64 rows, duplicated)
// BK=64, 4 waves (2x2), per-wave 4x4 fragments. LDS XOR-swizzled.
// T14 async-stage: next k-step's global loads issued before compute so their
// latency hides under ds_read+MFMA+barrier.
// ---------------------------------------------------------------------------
__global__ __launch_bounds__(256) void kxqh_kernel(
    const float* __restrict__ keys,   // [8192,512] f32
    const float* __restrict__ query,  // [64,512]   f32
    const float* __restrict__ Wx,     // [512,512]  f32
    const float* __restrict__ Wh,     // [512,512]  f32
    const float* __restrict__ bh,     // [512]      f32
    f16* __restrict__ kx,             // [8192,512] f16
    f16* __restrict__ qh) {           // [64,512]   f16
  __shared__ char lds[32768] __attribute__((aligned(128)));
  const int t = threadIdx.x;
  const int lane = t & 63;
  const int w = t >> 6;
  const int wr = w >> 1, wc = w & 1;
  const int fq = lane >> 4, fr = lane & 15;
  const bool isQH = (blockIdx.x == 64);
  const int rowA0 = blockIdx.x * 128;
  const int m0 = blockIdx.y * 128;
  const float* Ap = isQH ? query : keys;
  const float* Wp = isQH ? Wh : Wx;

  f32x4 acc[4][4] = {};
  float4 ra[8], rb[8];

#define LOADK(K0)                                                              \
  do {                                                                         \
    _Pragma("unroll") for (int i = 0; i < 8; ++i) {                            \
      int flat = t * 4 + i * 1024;                                             \
      int row = flat >> 6, col = flat & 63;                                    \
      int arow = isQH ? (row & 63) : (rowA0 + row);                            \
      ra[i] = *reinterpret_cast<const float4*>(Ap + (size_t)arow * DD + (K0) + col); \
      rb[i] = *reinterpret_cast<const float4*>(Wp + (size_t)(m0 + row) * DD + (K0) + col); \
    }                                                                          \
  } while (0)

  LOADK(0);
  for (int s = 0; s < 8; ++s) {
    // ---- write phase: waits the loads issued last iteration ----
    #pragma unroll
    for (int i = 0; i < 8; ++i) {
      int flat = t * 4 + i * 1024;
      int row = flat >> 6, col = flat & 63;
      f16x4 ha, hb;
      ha[0] = (f16)ra[i].x; ha[1] = (f16)ra[i].y; ha[2] = (f16)ra[i].z; ha[3] = (f16)ra[i].w;
      hb[0] = (f16)rb[i].x; hb[1] = (f16)rb[i].y; hb[2] = (f16)rb[i].z; hb[3] = (f16)rb[i].w;
      int byte = (row * 128 + col * 2) ^ ((row & 7) << 4);
      *reinterpret_cast<f16x4*>(lds + byte) = ha;
      *reinterpret_cast<f16x4*>(lds + 16384 + byte) = hb;
    }
    if (s < 7) LOADK((s + 1) * 64);   // in flight across compute
    __syncthreads();
    // ---- compute: 2 k-halves x 16 MFMA ----
    #pragma unroll
    for (int kh = 0; kh < 2; ++kh) {
      f16x8 af[4], bfr[4];
      #pragma unroll
      for (int mi = 0; mi < 4; ++mi) {
        int row = wr * 64 + mi * 16 + fr;
        int byte = (row * 128 + kh * 64 + fq * 16) ^ ((row & 7) << 4);
        af[mi] = *reinterpret_cast<const f16x8*>(lds + byte);
      }
      #pragma unroll
      for (int ni = 0; ni < 4; ++ni) {
        int row = wc * 64 + ni * 16 + fr;
        int byte = ((row * 128 + kh * 64 + fq * 16) ^ ((row & 7) << 4)) + 16384;
        bfr[ni] = *reinterpret_cast<const f16x8*>(lds + byte);
      }
      #pragma unroll
      for (int mi = 0; mi < 4; ++mi)
        #pragma unroll
        for (int ni = 0; ni < 4; ++ni)
          acc[mi][ni] = __builtin_amdgcn_mfma_f32_16x16x32_f16(
              af[mi], bfr[ni], acc[mi][ni], 0, 0, 0);
    }
    __syncthreads();
  }
#undef LOADK
  if (isQH) {
    #pragma unroll
    for (int mi = 0; mi < 4; ++mi) {
      #pragma unroll
      for (int ni = 0; ni < 4; ++ni) {
        int row = wr * 64 + mi * 16 + fq * 4;
        int col = m0 + wc * 64 + ni * 16 + fr;
        if (row < 64) {
          float bias = bh[col];
          #pragma unroll
          for (int r = 0; r < 4; ++r)
            qh[(size_t)(row + r) * DD + col] = (f16)(acc[mi][ni][r] + bias);
        }
      }
    }
  } else {
    #pragma unroll
    for (int mi = 0; mi < 4; ++mi) {
      #pragma unroll
      for (int ni = 0; ni < 4; ++ni) {
        int row = rowA0 + wr * 64 + mi * 16 + fq * 4;
        int col = m0 + wc * 64 + ni * 16 + fr;
        #pragma unroll
        for (int r = 0; r < 4; ++r)
          kx[(size_t)(row + r) * DD + col] = (f16)acc[mi][ni][r];
      }
    }
  }
}

// ---------------------------------------------------------------------------
// K2: scores[b,q,l] = sum_m w[m]*relu(kx[b,l,m]+qh[q,m]) — packed f16 math.
// Block = (b, l-tile of 32) x all 64 q. Grid 256 (1 block/CU).
// Thread: 2 l x 4 q register tile (R=8): 7 b128 LDS reads per 16 results.
// ---------------------------------------------------------------------------
__global__ __launch_bounds__(256) void score4_kernel(
    const f16* __restrict__ kx,   // [8,1024,512] f16
    const f16* __restrict__ qh,   // [64,512] f16
    const float* __restrict__ w,  // [512] f32
    float* __restrict__ sc) {     // [8,64,1024] f32
  const int b = blockIdx.x & 7;
  const int l0 = (blockIdx.x >> 3) * 32;
  const int t = threadIdx.x;
  __shared__ __align__(16) f16 kxs[32][136];   // 272B row stride, all rows 16B-aligned
  __shared__ __align__(16) f16 qhs[64][136];
  __shared__ __align__(16) f16 wsf[DD];
  if (t < 128) {
    float4 wv = *reinterpret_cast<const float4*>(w + t * 4);
    f16x4 hv; hv[0] = (f16)wv.x; hv[1] = (f16)wv.y; hv[2] = (f16)wv.z; hv[3] = (f16)wv.w;
    *reinterpret_cast<f16x4*>(&wsf[t * 4]) = hv;
  }
  const int qb = t & 15;          // q in {qb, qb+16, qb+32, qb+48}
  const int lt = (t >> 4) * 2;    // l in {lt, lt+1}
  float acc[2][4] = {};
  for (int m0 = 0; m0 < DD; m0 += 128) {
    #pragma unroll
    for (int p = 0; p < 2; ++p) {  // kxs: 32 x 128 f16
      int flat = t * 8 + p * 2048;
      int row = flat >> 7, col = flat & 127;
      *reinterpret_cast<uint4*>(&kxs[row][col]) =
          *reinterpret_cast<const uint4*>(kx + (size_t)(b * LL + l0 + row) * DD + m0 + col);
    }
    #pragma unroll
    for (int p = 0; p < 4; ++p) {  // qhs: 64 x 128 f16
      int flat = t * 8 + p * 2048;
      int row = flat >> 7, col = flat & 127;
      *reinterpret_cast<uint4*>(&qhs[row][col]) =
          *reinterpret_cast<const uint4*>(qh + (size_t)row * DD + m0 + col);
    }
    __syncthreads();
    #pragma unroll 2
    for (int mm = 0; mm < 128; mm += 8) {
      F16x8u kv0, kv1, wv;
      kv0.v = *reinterpret_cast<const f16x8*>(&kxs[lt][mm]);
      kv1.v = *reinterpret_cast<const f16x8*>(&kxs[lt + 1][mm]);
      wv.v = *reinterpret_cast<const f16x8*>(&wsf[m0 + mm]);
      #pragma unroll
      for (int j = 0; j < 4; ++j) {
        F16x8u qv, g0, g1;
        qv.v = *reinterpret_cast<const f16x8*>(&qhs[qb + 16 * j][mm]);
        f16x8 zz = {};
        g0.v = __builtin_elementwise_max(kv0.v + qv.v, zz);
        g1.v = __builtin_elementwise_max(kv1.v + qv.v, zz);
        #pragma unroll
        for (int c = 0; c < 4; ++c) {
          acc[0][j] = __builtin_amdgcn_fdot2(g0.h[c], wv.h[c], acc[0][j], false);
          acc[1][j] = __builtin_amdgcn_fdot2(g1.h[c], wv.h[c], acc[1][j], false);
        }
      }
    }
    __syncthreads();
  }
  #pragma unroll
  for (int i = 0; i < 2; ++i)
    #pragma unroll
    for (int j = 0; j < 4; ++j)
      sc[((size_t)b * L1 + qb + 16 * j) * LL + l0 + lt + i] = acc[i][j];
}

// ---------------------------------------------------------------------------
// K3: fused softmax + PV GEMM, direct output (no split-K, no reduce pass).
// Grid 256 = 8 b (low bits -> per-XCD L2 residency of sc[b], V[b]) x 32
// d-tiles of 16. Per block: pass1 row-max over sc[b] (64x1024), then 8
// l-chunks: es[64q][128l] = exp(sc - rowmax) in f16 (XOR-swizzled) and
// vt[16d][128l] = V^T in f16, 4 MFMA per wave per chunk. Softmax sums
// accumulated per-thread in fixed order, combined deterministically; the
// epilogue scales by 1/S. Depth-1 prefetch of next chunk's global loads.
// ---------------------------------------------------------------------------
__global__ __launch_bounds__(256) void fso_kernel(
    const float* __restrict__ sc,  // [8,64,1024] f32
    const float* __restrict__ v,   // [8,1024,512] f32
    float* __restrict__ out) {     // [8,64,512] f32
  __shared__ __align__(16) char es[64 * 256];   // 16 KB, swizzled f16 rows
  __shared__ __align__(16) char vt[16 * 256];   // 4 KB, swizzled f16 rows
  __shared__ float redm[256];
  __shared__ float rowm[64];
  __shared__ float rowinv[64];
  __shared__ float spart[64][17];
  const int t = threadIdx.x;
  const int lane = t & 63;
  const int w = t >> 6;
  const int fq = lane >> 4, fr = lane & 15;
  const int bid = blockIdx.x;
  const int b = bid & 7;
  const int d0 = (bid >> 3) * 16;
  const float* scb = sc + (size_t)b * L1 * LL;
  const float* vb = v + (size_t)b * LL * DD;

  const int eq = t >> 4;        // es row base (0..15), rows eq+16p
  const int ec8 = t & 15;       // es col8 (l = ec8*8 within chunk)
  const int vl = t >> 1;        // vt l (0..127)
  const int vdh = (t & 1) * 8;  // vt d half (0 or 8)
  float4 rsc[4][2];
  float4 rv[2];

#define LOADC(LC)                                                              \
  do {                                                                         \
    _Pragma("unroll") for (int p = 0; p < 4; ++p) {                            \
      const float* src = scb + (size_t)(eq + p * 16) * LL + (LC) * 128 + ec8 * 8; \
      rsc[p][0] = *reinterpret_cast<const float4*>(src);                       \
      rsc[p][1] = *reinterpret_cast<const float4*>(src + 4);                   \
    }                                                                          \
    const float* vsrc = vb + (size_t)((LC) * 128 + vl) * DD + d0 + vdh;        \
    rv[0] = *reinterpret_cast<const float4*>(vsrc);                            \
    rv[1] = *reinterpret_cast<const float4*>(vsrc + 4);                        \
  } while (0)

  LOADC(0);   // issue chunk-0 loads; latency hides under pass 1

  // ---- pass 1: per-row max over sc[b] ----
  {
    const int q = t >> 2, part = t & 3;
    const float* r = scb + (size_t)q * LL + part * 256;
    float m = -3.4e38f;
    #pragma unroll 8
    for (int i = 0; i < 64; ++i) {
      float4 x = *reinterpret_cast<const float4*>(r + i * 4);
      m = fmaxf(m, fmaxf(fmaxf(x.x, x.y), fmaxf(x.z, x.w)));
    }
    redm[t] = m;
  }
  __syncthreads();
  if (t < 64) {
    float4 mm = *reinterpret_cast<const float4*>(&redm[t * 4]);
    rowm[t] = fmaxf(fmaxf(mm.x, mm.y), fmaxf(mm.z, mm.w));
  }
  __syncthreads();
  float rmv[4];
  #pragma unroll
  for (int p = 0; p < 4; ++p) rmv[p] = rowm[eq + p * 16];
  float spp[4] = {0.f, 0.f, 0.f, 0.f};
  f32x4 acc = {};

  for (int c = 0; c < 8; ++c) {
    // ---- write phase: exp -> es, transpose V -> vt (waits chunk-c loads) ----
    #pragma unroll
    for (int p = 0; p < 4; ++p) {
      int q = eq + p * 16;
      float xs[8] = {rsc[p][0].x, rsc[p][0].y, rsc[p][0].z, rsc[p][0].w,
                     rsc[p][1].x, rsc[p][1].y, rsc[p][1].z, rsc[p][1].w};
      f16x8 h;
      #pragma unroll
      for (int j = 0; j < 8; ++j) {
        float e = __expf(xs[j] - rmv[p]);
        spp[p] += e;
        h[j] = (f16)e;
      }
      int byte = q * 256 + ((ec8 * 16) ^ ((q & 7) << 4));
      *reinterpret_cast<f16x8*>(es + byte) = h;
    }
    {
      float vs[8] = {rv[0].x, rv[0].y, rv[0].z, rv[0].w,
                     rv[1].x, rv[1].y, rv[1].z, rv[1].w};
      #pragma unroll
      for (int j = 0; j < 8; ++j) {
        int d = vdh + j;
        int byte = d * 256 + ((2 * vl) ^ ((d & 7) << 4));
        *reinterpret_cast<f16*>(vt + byte) = (f16)vs[j];
      }
    }
    if (c < 7) LOADC(c + 1);   // in flight across MFMA + barrier
    __syncthreads();
    // ---- MFMA: acc[q-frag of this wave][d0..d0+16] += es . vt^T ----
    #pragma unroll
    for (int ks = 0; ks < 4; ++ks) {
      int qa = w * 16 + fr;
      int colb = ks * 64 + fq * 16;
      f16x8 a = *reinterpret_cast<const f16x8*>(es + qa * 256 + (colb ^ ((qa & 7) << 4)));
      f16x8 bb = *reinterpret_cast<const f16x8*>(vt + fr * 256 + (colb ^ ((fr & 7) << 4)));
      acc = __builtin_amdgcn_mfma_f32_16x16x32_f16(a, bb, acc, 0, 0, 0);
    }
    __syncthreads();
  }
#undef LOADC
  // ---- deterministic softmax-sum combine ----
  #pragma unroll
  for (int p = 0; p < 4; ++p) spart[eq + p * 16][ec8] = spp[p];
  __syncthreads();
  if (t < 64) {
    float S = 0.f;
    #pragma unroll
    for (int i = 0; i < 16; ++i) S += spart[t][i];
    rowinv[t] = 1.f / S;
  }
  __syncthreads();
  // ---- epilogue: scale by 1/S and store ----
  #pragma unroll
  for (int r = 0; r < 4; ++r) {
    int q = w * 16 + fq * 4 + r;
    out[((size_t)b * L1 + q) * DD + d0 + fr] = acc[r] * rowinv[q];
  }
}

// ---------------------------------------------------------------------------
extern "C" void kernel_launch(void* const* d_in, const int* in_sizes, int n_in,
                              void* d_out, int out_size, void* d_ws, size_t ws_size,
                              hipStream_t stream) {
  const float* query  = (const float*)d_in[0];  // [64,512]
  const float* keys   = (const float*)d_in[1];  // [8,1024,512]
  const float* values = (const float*)d_in[2];  // [8,1024,512]
  const float* Wx     = (const float*)d_in[3];  // [512,512]
  const float* Wh     = (const float*)d_in[4];  // [512,512]
  const float* bh     = (const float*)d_in[5];  // [512]
  const float* w      = (const float*)d_in[6];  // [512]
  float* out = (float*)d_out;                   // [8,64,512]

  char* ws = (char*)d_ws;
  f16*   kx = (f16*)ws;                  // 8 MB
  f16*   qh = (f16*)(ws + 8388608);      // 64 KB
  float* sc = (float*)(ws + 8454144);    // 2 MB

  kxqh_kernel<<<dim3(65, DD / 128), 256, 0, stream>>>(keys, query, Wx, Wh, bh, kx, qh);
  score4_kernel<<<BB * (LL / 32), 256, 0, stream>>>(kx, qh, w, sc);
  fso_kernel<<<256, 256, 0, stream>>>(sc, values, out);
}

// Round 7
// 59.504 us; speedup vs baseline: 1.2125x; 1.2125x over previous
//
#include <hip/hip_runtime.h>
#include <hip/hip_bf16.h>

// Problem constants
#define BB 8
#define L1 64
#define LL 1024
#define DD 512   // DIM_IN == DIM_H == DIM_M == 512

typedef float f32x4 __attribute__((ext_vector_type(4)));
typedef _Float16 f16;
typedef _Float16 f16x2 __attribute__((ext_vector_type(2)));
typedef _Float16 f16x4 __attribute__((ext_vector_type(4)));
typedef _Float16 f16x8 __attribute__((ext_vector_type(8)));

union F16x8u { f16x8 v; f16x2 h[4]; };

// ---------------------------------------------------------------------------
// K1: fused kx + qh GEMM via f16 MFMA 16x16x32.
// 128x64 output tiles, grid 520 (2 blocks/CU):
//   bid < 512: rt = bid&63 (keys rows), mt = bid>>6 (Wx 64-col tile)
//              -> same rt lands on same XCD (bid%8 = rt%8): keys L2-resident.
//   bid >= 512: qh tile (query @ Wh^T + bh), mt = bid-512.
// BK=64, 4 waves (2x2: 64 rows x 32 cols each), per-wave 4x2 fragments.
// T14 reg prefetch of next k-step; LDS XOR-swizzled.
// ---------------------------------------------------------------------------
__global__ __launch_bounds__(256, 2) void kxqh_kernel(
    const float* __restrict__ keys,   // [8192,512] f32
    const float* __restrict__ query,  // [64,512]   f32
    const float* __restrict__ Wx,     // [512,512]  f32
    const float* __restrict__ Wh,     // [512,512]  f32
    const float* __restrict__ bh,     // [512]      f32
    f16* __restrict__ kx,             // [8192,512] f16
    f16* __restrict__ qh) {           // [64,512]   f16
  __shared__ char lds[24576] __attribute__((aligned(128)));  // A 16KB | B 8KB
  const int t = threadIdx.x;
  const int lane = t & 63;
  const int w = t >> 6;
  const int wr = w >> 1, wc = w & 1;
  const int fq = lane >> 4, fr = lane & 15;
  const int bid = blockIdx.x;
  const bool isQH = (bid >= 512);
  const int rt = isQH ? 0 : (bid & 63);
  const int mt = isQH ? (bid - 512) : (bid >> 6);
  const int rowA0 = rt * 128;
  const int m0 = mt * 64;
  const float* Ap = isQH ? query : keys;
  const float* Wp = isQH ? Wh : Wx;

  f32x4 acc[4][2] = {};
  float4 ra[8], rb[4];

#define LOADK(K0)                                                              \
  do {                                                                         \
    _Pragma("unroll") for (int i = 0; i < 8; ++i) {                            \
      int flat = t * 4 + i * 1024;                                             \
      int row = flat >> 6, col = flat & 63;                                    \
      int arow = isQH ? (row & 63) : (rowA0 + row);                            \
      ra[i] = *reinterpret_cast<const float4*>(Ap + (size_t)arow * DD + (K0) + col); \
    }                                                                          \
    _Pragma("unroll") for (int i = 0; i < 4; ++i) {                            \
      int flat = t * 4 + i * 1024;                                             \
      int row = flat >> 6, col = flat & 63;                                    \
      rb[i] = *reinterpret_cast<const float4*>(Wp + (size_t)(m0 + row) * DD + (K0) + col); \
    }                                                                          \
  } while (0)

  LOADK(0);
  for (int s = 0; s < 8; ++s) {
    // ---- write phase (waits loads issued last iteration) ----
    #pragma unroll
    for (int i = 0; i < 8; ++i) {
      int flat = t * 4 + i * 1024;
      int row = flat >> 6, col = flat & 63;
      f16x4 ha;
      ha[0] = (f16)ra[i].x; ha[1] = (f16)ra[i].y; ha[2] = (f16)ra[i].z; ha[3] = (f16)ra[i].w;
      int byte = (row * 128 + col * 2) ^ ((row & 7) << 4);
      *reinterpret_cast<f16x4*>(lds + byte) = ha;
    }
    #pragma unroll
    for (int i = 0; i < 4; ++i) {
      int flat = t * 4 + i * 1024;
      int row = flat >> 6, col = flat & 63;
      f16x4 hb;
      hb[0] = (f16)rb[i].x; hb[1] = (f16)rb[i].y; hb[2] = (f16)rb[i].z; hb[3] = (f16)rb[i].w;
      int byte = 16384 + ((row * 128 + col * 2) ^ ((row & 7) << 4));
      *reinterpret_cast<f16x4*>(lds + byte) = hb;
    }
    if (s < 7) LOADK((s + 1) * 64);   // in flight across compute
    __syncthreads();
    // ---- compute: 2 k-halves x 8 MFMA ----
    #pragma unroll
    for (int kh = 0; kh < 2; ++kh) {
      f16x8 af[4], bf[2];
      #pragma unroll
      for (int mi = 0; mi < 4; ++mi) {
        int row = wr * 64 + mi * 16 + fr;
        int byte = (row * 128 + kh * 64 + fq * 16) ^ ((row & 7) << 4);
        af[mi] = *reinterpret_cast<const f16x8*>(lds + byte);
      }
      #pragma unroll
      for (int ni = 0; ni < 2; ++ni) {
        int row = wc * 32 + ni * 16 + fr;
        int byte = 16384 + ((row * 128 + kh * 64 + fq * 16) ^ ((row & 7) << 4));
        bf[ni] = *reinterpret_cast<const f16x8*>(lds + byte);
      }
      #pragma unroll
      for (int mi = 0; mi < 4; ++mi)
        #pragma unroll
        for (int ni = 0; ni < 2; ++ni)
          acc[mi][ni] = __builtin_amdgcn_mfma_f32_16x16x32_f16(
              af[mi], bf[ni], acc[mi][ni], 0, 0, 0);
    }
    __syncthreads();
  }
#undef LOADK
  if (isQH) {
    #pragma unroll
    for (int mi = 0; mi < 4; ++mi) {
      #pragma unroll
      for (int ni = 0; ni < 2; ++ni) {
        int row = wr * 64 + mi * 16 + fq * 4;
        int col = m0 + wc * 32 + ni * 16 + fr;
        if (row < 64) {
          float bias = bh[col];
          #pragma unroll
          for (int r = 0; r < 4; ++r)
            qh[(size_t)(row + r) * DD + col] = (f16)(acc[mi][ni][r] + bias);
        }
      }
    }
  } else {
    #pragma unroll
    for (int mi = 0; mi < 4; ++mi) {
      #pragma unroll
      for (int ni = 0; ni < 2; ++ni) {
        int row = rowA0 + wr * 64 + mi * 16 + fq * 4;
        int col = m0 + wc * 32 + ni * 16 + fr;
        #pragma unroll
        for (int r = 0; r < 4; ++r)
          kx[(size_t)(row + r) * DD + col] = (f16)acc[mi][ni][r];
      }
    }
  }
}

// ---------------------------------------------------------------------------
// K2: scores[b,q,l] = sum_m w[m]*relu(kx[b,l,m]+qh[q,m]) — packed f16 math.
// Block = (b, l-tile of 32) x all 64 q. Grid 256.
// Thread: 2 l x 4 q register tile. T14 prefetch of next m-chunk.
// Also emits pmax[b][q][ltile] = max_l(scores) for fso's row-max.
// ---------------------------------------------------------------------------
__global__ __launch_bounds__(256, 2) void score4_kernel(
    const f16* __restrict__ kx,   // [8,1024,512] f16
    const f16* __restrict__ qh,   // [64,512] f16
    const float* __restrict__ w,  // [512] f32
    float* __restrict__ sc,       // [8,64,1024] f32
    float* __restrict__ pmax) {   // [8,64,32] f32
  const int b = blockIdx.x & 7;
  const int l0 = (blockIdx.x >> 3) * 32;
  const int t = threadIdx.x;
  __shared__ __align__(16) f16 kxs[32][136];   // 272B row stride
  __shared__ __align__(16) f16 qhs[64][136];
  __shared__ __align__(16) f16 wsf[DD];
  __shared__ float smax[64][17];
  if (t < 128) {
    float4 wv = *reinterpret_cast<const float4*>(w + t * 4);
    f16x4 hv; hv[0] = (f16)wv.x; hv[1] = (f16)wv.y; hv[2] = (f16)wv.z; hv[3] = (f16)wv.w;
    *reinterpret_cast<f16x4*>(&wsf[t * 4]) = hv;
  }
  const int qb = t & 15;          // q in {qb, qb+16, qb+32, qb+48}
  const int lt = (t >> 4) * 2;    // l in {lt, lt+1}
  float acc[2][4] = {};
  uint4 rkx[2], rqh[4];

#define LOADM(M0)                                                              \
  do {                                                                         \
    _Pragma("unroll") for (int p = 0; p < 2; ++p) {                            \
      int flat = t * 8 + p * 2048;                                             \
      int row = flat >> 7, col = flat & 127;                                   \
      rkx[p] = *reinterpret_cast<const uint4*>(kx + (size_t)(b * LL + l0 + row) * DD + (M0) + col); \
    }                                                                          \
    _Pragma("unroll") for (int p = 0; p < 4; ++p) {                            \
      int flat = t * 8 + p * 2048;                                             \
      int row = flat >> 7, col = flat & 127;                                   \
      rqh[p] = *reinterpret_cast<const uint4*>(qh + (size_t)row * DD + (M0) + col); \
    }                                                                          \
  } while (0)

  LOADM(0);
  for (int m0 = 0; m0 < DD; m0 += 128) {
    #pragma unroll
    for (int p = 0; p < 2; ++p) {
      int flat = t * 8 + p * 2048;
      int row = flat >> 7, col = flat & 127;
      *reinterpret_cast<uint4*>(&kxs[row][col]) = rkx[p];
    }
    #pragma unroll
    for (int p = 0; p < 4; ++p) {
      int flat = t * 8 + p * 2048;
      int row = flat >> 7, col = flat & 127;
      *reinterpret_cast<uint4*>(&qhs[row][col]) = rqh[p];
    }
    if (m0 < DD - 128) LOADM(m0 + 128);
    __syncthreads();
    #pragma unroll 2
    for (int mm = 0; mm < 128; mm += 8) {
      F16x8u kv0, kv1, wv;
      kv0.v = *reinterpret_cast<const f16x8*>(&kxs[lt][mm]);
      kv1.v = *reinterpret_cast<const f16x8*>(&kxs[lt + 1][mm]);
      wv.v = *reinterpret_cast<const f16x8*>(&wsf[m0 + mm]);
      #pragma unroll
      for (int j = 0; j < 4; ++j) {
        F16x8u qv, g0, g1;
        qv.v = *reinterpret_cast<const f16x8*>(&qhs[qb + 16 * j][mm]);
        f16x8 zz = {};
        g0.v = __builtin_elementwise_max(kv0.v + qv.v, zz);
        g1.v = __builtin_elementwise_max(kv1.v + qv.v, zz);
        #pragma unroll
        for (int c = 0; c < 4; ++c) {
          acc[0][j] = __builtin_amdgcn_fdot2(g0.h[c], wv.h[c], acc[0][j], false);
          acc[1][j] = __builtin_amdgcn_fdot2(g1.h[c], wv.h[c], acc[1][j], false);
        }
      }
    }
    __syncthreads();
  }
#undef LOADM
  #pragma unroll
  for (int i = 0; i < 2; ++i)
    #pragma unroll
    for (int j = 0; j < 4; ++j)
      sc[((size_t)b * L1 + qb + 16 * j) * LL + l0 + lt + i] = acc[i][j];
  // per-(q, l-tile) partial max for fso
  #pragma unroll
  for (int j = 0; j < 4; ++j)
    smax[qb + 16 * j][t >> 4] = fmaxf(acc[0][j], acc[1][j]);
  __syncthreads();
  if (t < 64) {
    float m = smax[t][0];
    #pragma unroll
    for (int i = 1; i < 16; ++i) m = fmaxf(m, smax[t][i]);
    pmax[((size_t)b * L1 + t) * 32 + (l0 >> 5)] = m;
  }
}

// ---------------------------------------------------------------------------
// K3: fused softmax + PV GEMM, direct output.
// Grid 256 = 8 b x 32 d-tiles(16). Row-max from pmax (no sc re-read pass).
// 8 l-chunks: es[64q][128l] = exp(sc-rowmax) f16 (XOR-swizzled), vt[16d][128l]
// = V^T f16; 4 MFMA/wave/chunk; deterministic sum combine; scale by 1/S.
// Depth-1 prefetch of next chunk's global loads.
// ---------------------------------------------------------------------------
__global__ __launch_bounds__(256) void fso_kernel(
    const float* __restrict__ sc,   // [8,64,1024] f32
    const float* __restrict__ pmax, // [8,64,32] f32
    const float* __restrict__ v,    // [8,1024,512] f32
    float* __restrict__ out) {      // [8,64,512] f32
  __shared__ __align__(16) char es[64 * 256];   // 16 KB, swizzled f16 rows
  __shared__ __align__(16) char vt[16 * 256];   // 4 KB, swizzled f16 rows
  __shared__ float rowm[64];
  __shared__ float rowinv[64];
  __shared__ float spart[64][17];
  const int t = threadIdx.x;
  const int lane = t & 63;
  const int w = t >> 6;
  const int fq = lane >> 4, fr = lane & 15;
  const int bid = blockIdx.x;
  const int b = bid & 7;
  const int d0 = (bid >> 3) * 16;
  const float* scb = sc + (size_t)b * L1 * LL;
  const float* vb = v + (size_t)b * LL * DD;

  const int eq = t >> 4;        // es row base (0..15), rows eq+16p
  const int ec8 = t & 15;       // es col8 (l = ec8*8 within chunk)
  const int vl = t >> 1;        // vt l (0..127)
  const int vdh = (t & 1) * 8;  // vt d half (0 or 8)
  float4 rsc[4][2];
  float4 rv[2];

#define LOADC(LC)                                                              \
  do {                                                                         \
    _Pragma("unroll") for (int p = 0; p < 4; ++p) {                            \
      const float* src = scb + (size_t)(eq + p * 16) * LL + (LC) * 128 + ec8 * 8; \
      rsc[p][0] = *reinterpret_cast<const float4*>(src);                       \
      rsc[p][1] = *reinterpret_cast<const float4*>(src + 4);                   \
    }                                                                          \
    const float* vsrc = vb + (size_t)((LC) * 128 + vl) * DD + d0 + vdh;        \
    rv[0] = *reinterpret_cast<const float4*>(vsrc);                            \
    rv[1] = *reinterpret_cast<const float4*>(vsrc + 4);                        \
  } while (0)

  LOADC(0);
  // ---- row max from score4 partials ----
  if (t < 64) {
    const float* pm = pmax + ((size_t)b * L1 + t) * 32;
    float4 m4 = *reinterpret_cast<const float4*>(pm);
    #pragma unroll
    for (int i = 1; i < 8; ++i) {
      float4 x = *reinterpret_cast<const float4*>(pm + i * 4);
      m4.x = fmaxf(m4.x, x.x); m4.y = fmaxf(m4.y, x.y);
      m4.z = fmaxf(m4.z, x.z); m4.w = fmaxf(m4.w, x.w);
    }
    rowm[t] = fmaxf(fmaxf(m4.x, m4.y), fmaxf(m4.z, m4.w));
  }
  __syncthreads();
  float rmv[4];
  #pragma unroll
  for (int p = 0; p < 4; ++p) rmv[p] = rowm[eq + p * 16];
  float spp[4] = {0.f, 0.f, 0.f, 0.f};
  f32x4 acc = {};

  for (int c = 0; c < 8; ++c) {
    // ---- write phase: exp -> es, transpose V -> vt ----
    #pragma unroll
    for (int p = 0; p < 4; ++p) {
      int q = eq + p * 16;
      float xs[8] = {rsc[p][0].x, rsc[p][0].y, rsc[p][0].z, rsc[p][0].w,
                     rsc[p][1].x, rsc[p][1].y, rsc[p][1].z, rsc[p][1].w};
      f16x8 h;
      #pragma unroll
      for (int j = 0; j < 8; ++j) {
        float e = __expf(xs[j] - rmv[p]);
        spp[p] += e;
        h[j] = (f16)e;
      }
      int byte = q * 256 + ((ec8 * 16) ^ ((q & 7) << 4));
      *reinterpret_cast<f16x8*>(es + byte) = h;
    }
    {
      float vs[8] = {rv[0].x, rv[0].y, rv[0].z, rv[0].w,
                     rv[1].x, rv[1].y, rv[1].z, rv[1].w};
      #pragma unroll
      for (int j = 0; j < 8; ++j) {
        int d = vdh + j;
        int byte = d * 256 + ((2 * vl) ^ ((d & 7) << 4));
        *reinterpret_cast<f16*>(vt + byte) = (f16)vs[j];
      }
    }
    if (c < 7) LOADC(c + 1);   // in flight across MFMA + barrier
    __syncthreads();
    // ---- MFMA: wave w covers q rows w*16..+15, d = d0..d0+15 ----
    #pragma unroll
    for (int ks = 0; ks < 4; ++ks) {
      int qa = w * 16 + fr;
      int colb = ks * 64 + fq * 16;
      f16x8 a = *reinterpret_cast<const f16x8*>(es + qa * 256 + (colb ^ ((qa & 7) << 4)));
      f16x8 bb = *reinterpret_cast<const f16x8*>(vt + fr * 256 + (colb ^ ((fr & 7) << 4)));
      acc = __builtin_amdgcn_mfma_f32_16x16x32_f16(a, bb, acc, 0, 0, 0);
    }
    __syncthreads();
  }
#undef LOADC
  // ---- deterministic softmax-sum combine ----
  #pragma unroll
  for (int p = 0; p < 4; ++p) spart[eq + p * 16][ec8] = spp[p];
  __syncthreads();
  if (t < 64) {
    float S = 0.f;
    #pragma unroll
    for (int i = 0; i < 16; ++i) S += spart[t][i];
    rowinv[t] = 1.f / S;
  }
  __syncthreads();
  #pragma unroll
  for (int r = 0; r < 4; ++r) {
    int q = w * 16 + fq * 4 + r;
    out[((size_t)b * L1 + q) * DD + d0 + fr] = acc[r] * rowinv[q];
  }
}

// ---------------------------------------------------------------------------
extern "C" void kernel_launch(void* const* d_in, const int* in_sizes, int n_in,
                              void* d_out, int out_size, void* d_ws, size_t ws_size,
                              hipStream_t stream) {
  const float* query  = (const float*)d_in[0];  // [64,512]
  const float* keys   = (const float*)d_in[1];  // [8,1024,512]
  const float* values = (const float*)d_in[2];  // [8,1024,512]
  const float* Wx     = (const float*)d_in[3];  // [512,512]
  const float* Wh     = (const float*)d_in[4];  // [512,512]
  const float* bh     = (const float*)d_in[5];  // [512]
  const float* w      = (const float*)d_in[6];  // [512]
  float* out = (float*)d_out;                   // [8,64,512]

  char* ws = (char*)d_ws;
  f16*   kx   = (f16*)ws;                  // 8 MB
  f16*   qh   = (f16*)(ws + 8388608);      // 64 KB
  float* sc   = (float*)(ws + 8454144);    // 2 MB
  float* pmax = (float*)(ws + 10551296);   // 64 KB

  kxqh_kernel<<<520, 256, 0, stream>>>(keys, query, Wx, Wh, bh, kx, qh);
  score4_kernel<<<BB * (LL / 32), 256, 0, stream>>>(kx, qh, w, sc, pmax);
  fso_kernel<<<256, 256, 0, stream>>>(sc, pmax, values, out);
}

// Round 8
// 58.688 us; speedup vs baseline: 1.2294x; 1.0139x over previous
//
#include <hip/hip_runtime.h>
#include <hip/hip_bf16.h>

// Problem constants
#define BB 8
#define L1 64
#define LL 1024
#define DD 512   // DIM_IN == DIM_H == DIM_M == 512

typedef float f32x4 __attribute__((ext_vector_type(4)));
typedef _Float16 f16;
typedef _Float16 f16x2 __attribute__((ext_vector_type(2)));
typedef _Float16 f16x4 __attribute__((ext_vector_type(4)));
typedef _Float16 f16x8 __attribute__((ext_vector_type(8)));

union F16x8u { f16x8 v; f16x2 h[4]; };

// ---------------------------------------------------------------------------
// K1: qh[q,m] = query @ Wh^T + bh  -> f16.  MFMA, grid 8 (64 m-cols each).
// Per k-chunk (BK=64): stage query/Wh slices as f16 [64][72] (stride 144B =
// 9 LDS units -> conflict-free), 8 MFMA/wave. T14 reg prefetch.
// ---------------------------------------------------------------------------
__global__ __launch_bounds__(256) void qh_kernel(
    const float* __restrict__ query,  // [64,512]
    const float* __restrict__ Wh,     // [512,512]
    const float* __restrict__ bh,     // [512]
    f16* __restrict__ qh) {           // [64,512] f16
  __shared__ char lds[18432] __attribute__((aligned(128)));  // qys@0, whs@9216
  const int t = threadIdx.x;
  const int lane = t & 63;
  const int wid = t >> 6;
  const int fq = lane >> 4, fr = lane & 15;
  const int m0 = blockIdx.x * 64;
  f32x4 acc[4] = {};
  float4 rq[4], rw[4];

#define LOADQ(KC)                                                              \
  do {                                                                         \
    _Pragma("unroll") for (int i = 0; i < 4; ++i) {                            \
      int slot = t + i * 256;                                                  \
      int row = slot >> 4, c4 = (slot & 15) * 4;                               \
      rq[i] = *reinterpret_cast<const float4*>(query + (size_t)row * DD + (KC)*64 + c4); \
      rw[i] = *reinterpret_cast<const float4*>(Wh + (size_t)(m0 + row) * DD + (KC)*64 + c4); \
    }                                                                          \
  } while (0)

  LOADQ(0);
  for (int kc = 0; kc < 8; ++kc) {
    #pragma unroll
    for (int i = 0; i < 4; ++i) {
      int slot = t + i * 256;
      int row = slot >> 4, c4 = (slot & 15) * 4;
      f16x4 hq, hw;
      hq[0] = (f16)rq[i].x; hq[1] = (f16)rq[i].y; hq[2] = (f16)rq[i].z; hq[3] = (f16)rq[i].w;
      hw[0] = (f16)rw[i].x; hw[1] = (f16)rw[i].y; hw[2] = (f16)rw[i].z; hw[3] = (f16)rw[i].w;
      *reinterpret_cast<f16x4*>(lds + row * 144 + c4 * 2) = hq;
      *reinterpret_cast<f16x4*>(lds + 9216 + row * 144 + c4 * 2) = hw;
    }
    if (kc < 7) LOADQ(kc + 1);
    __syncthreads();
    #pragma unroll
    for (int kh = 0; kh < 2; ++kh) {
      f16x8 bf = *reinterpret_cast<const f16x8*>(
          lds + 9216 + (wid * 16 + fr) * 144 + kh * 64 + fq * 16);
      #pragma unroll
      for (int qf = 0; qf < 4; ++qf) {
        f16x8 af = *reinterpret_cast<const f16x8*>(
            lds + (qf * 16 + fr) * 144 + kh * 64 + fq * 16);
        acc[qf] = __builtin_amdgcn_mfma_f32_16x16x32_f16(af, bf, acc[qf], 0, 0, 0);
      }
    }
    __syncthreads();
  }
#undef LOADQ
  #pragma unroll
  for (int qf = 0; qf < 4; ++qf) {
    int m = m0 + wid * 16 + fr;
    float bias = bh[m];
    #pragma unroll
    for (int r = 0; r < 4; ++r)
      qh[(size_t)(qf * 16 + fq * 4 + r) * DD + m] = (f16)(acc[qf][r] + bias);
  }
}

// ---------------------------------------------------------------------------
// K2: fused kx-GEMM + score + pmax.  Grid 256 = (b = bid&7, l-tile of 32).
// Per block:
//   keysh [32][512] f16 XOR-swizzled (staged once from keys f32).
//   For each 128-m chunk mc: GEMM C[32][128] = keysh @ Wx_mc^T via 8 BK=64
//   k-chunks (wxs [128][72] f16, stride 9 units, T14 reg prefetch), C regs ->
//   kxs [32][136] LDS; stage qhs_mc [64][136] (aliases wxs); score4 inner
//   loop accumulates acc[2][4] (l = lq, lq+16 x 4 q) across chunks.
// Epilogue: sc writes + per-(q,ltile) pmax via f16 smax LDS.
// LDS total 63232 B.
// ---------------------------------------------------------------------------
#define KEYSH_OFF 0
#define WXS_OFF   32768
#define QHS_OFF   32768
#define KXS_OFF   51200
#define WSF_OFF   59904
#define SMAX_OFF  60928

__global__ __launch_bounds__(256) void kscore_kernel(
    const float* __restrict__ keys,  // [8,1024,512] f32
    const f16* __restrict__ qh,      // [64,512] f16
    const float* __restrict__ Wx,    // [512,512] f32
    const float* __restrict__ w,     // [512] f32
    float* __restrict__ sc,          // [8,64,1024] f32
    float* __restrict__ pmax) {      // [8,64,32] f32
  __shared__ char lds[63232] __attribute__((aligned(128)));
  const int t = threadIdx.x;
  const int lane = t & 63;
  const int wid = t >> 6;
  const int fq = lane >> 4, fr = lane & 15;
  const int b = blockIdx.x & 7;
  const int l0 = (blockIdx.x >> 3) * 32;
  const int qb = t & 15;        // q in {qb, qb+16, qb+32, qb+48}
  const int lq = t >> 4;        // l in {lq, lq+16}

  // ---- stage keysh [32][512] f16, XOR swizzle ----
  #pragma unroll
  for (int j = 0; j < 16; ++j) {
    int slot = t + j * 256;
    int l = slot >> 7, kcol = (slot & 127) * 4;
    float4 kv = *reinterpret_cast<const float4*>(
        keys + (size_t)(b * LL + l0 + l) * DD + kcol);
    f16x4 h;
    h[0] = (f16)kv.x; h[1] = (f16)kv.y; h[2] = (f16)kv.z; h[3] = (f16)kv.w;
    *reinterpret_cast<f16x4*>(
        lds + KEYSH_OFF + l * 1024 + ((kcol * 2) ^ ((l & 7) << 4))) = h;
  }
  if (t < 128) {
    float4 wv = *reinterpret_cast<const float4*>(w + t * 4);
    f16x4 hv; hv[0] = (f16)wv.x; hv[1] = (f16)wv.y; hv[2] = (f16)wv.z; hv[3] = (f16)wv.w;
    *reinterpret_cast<f16x4*>(lds + WSF_OFF + t * 8) = hv;
  }

  float4 rb[8];
#define LOADW(MC, KC)                                                          \
  do {                                                                         \
    _Pragma("unroll") for (int i = 0; i < 8; ++i) {                            \
      int slot = t + i * 256;                                                  \
      int m = slot >> 4, c4 = (slot & 15) * 4;                                 \
      rb[i] = *reinterpret_cast<const float4*>(                                \
          Wx + (size_t)((MC) * 128 + m) * DD + (KC) * 64 + c4);                \
    }                                                                          \
  } while (0)

  LOADW(0, 0);
  float acc[2][4] = {};

  for (int mc = 0; mc < 4; ++mc) {
    // ---- GEMM sub-phase: C[32 l][128 m] for this m-chunk ----
    f32x4 cacc[2][2] = {};
    for (int kc = 0; kc < 8; ++kc) {
      #pragma unroll
      for (int i = 0; i < 8; ++i) {
        int slot = t + i * 256;
        int m = slot >> 4, c4 = (slot & 15) * 4;
        f16x4 h;
        h[0] = (f16)rb[i].x; h[1] = (f16)rb[i].y; h[2] = (f16)rb[i].z; h[3] = (f16)rb[i].w;
        *reinterpret_cast<f16x4*>(lds + WXS_OFF + m * 144 + c4 * 2) = h;
      }
      {
        int nmc = mc, nkc = kc + 1;
        if (nkc == 8) { nmc++; nkc = 0; }
        if (nmc < 4) LOADW(nmc, nkc);
      }
      __syncthreads();
      #pragma unroll
      for (int kh = 0; kh < 2; ++kh) {
        f16x8 af[2], bf[2];
        #pragma unroll
        for (int lf = 0; lf < 2; ++lf) {
          int l = lf * 16 + fr;
          af[lf] = *reinterpret_cast<const f16x8*>(
              lds + KEYSH_OFF + l * 1024 +
              ((kc * 128 + kh * 64 + fq * 16) ^ ((l & 7) << 4)));
        }
        #pragma unroll
        for (int mf = 0; mf < 2; ++mf)
          bf[mf] = *reinterpret_cast<const f16x8*>(
              lds + WXS_OFF + (wid * 32 + mf * 16 + fr) * 144 + kh * 64 + fq * 16);
        #pragma unroll
        for (int lf = 0; lf < 2; ++lf)
          #pragma unroll
          for (int mf = 0; mf < 2; ++mf)
            cacc[lf][mf] = __builtin_amdgcn_mfma_f32_16x16x32_f16(
                af[lf], bf[mf], cacc[lf][mf], 0, 0, 0);
      }
      __syncthreads();
    }
    // ---- C regs -> kxs [32][136] f16 ----
    #pragma unroll
    for (int lf = 0; lf < 2; ++lf)
      #pragma unroll
      for (int mf = 0; mf < 2; ++mf)
        #pragma unroll
        for (int r = 0; r < 4; ++r) {
          int l = lf * 16 + fq * 4 + r;
          int m = wid * 32 + mf * 16 + fr;
          *reinterpret_cast<f16*>(lds + KXS_OFF + l * 272 + m * 2) =
              (f16)cacc[lf][mf][r];
        }
    // ---- stage qhs_mc [64][136] (aliases wxs; GEMM reads done) ----
    #pragma unroll
    for (int j = 0; j < 4; ++j) {
      int slot = t + j * 256;
      int row = slot >> 4, c8 = (slot & 15) * 8;
      uint4 qv = *reinterpret_cast<const uint4*>(qh + (size_t)row * DD + mc * 128 + c8);
      *reinterpret_cast<uint4*>(lds + QHS_OFF + row * 272 + c8 * 2) = qv;
    }
    __syncthreads();
    // ---- score sub-phase (score4 inner loop) ----
    #pragma unroll 2
    for (int mm = 0; mm < 128; mm += 8) {
      F16x8u kv0, kv1, wv;
      kv0.v = *reinterpret_cast<const f16x8*>(lds + KXS_OFF + lq * 272 + mm * 2);
      kv1.v = *reinterpret_cast<const f16x8*>(lds + KXS_OFF + (lq + 16) * 272 + mm * 2);
      wv.v = *reinterpret_cast<const f16x8*>(lds + WSF_OFF + (mc * 128 + mm) * 2);
      #pragma unroll
      for (int j = 0; j < 4; ++j) {
        F16x8u qv, g0, g1;
        qv.v = *reinterpret_cast<const f16x8*>(
            lds + QHS_OFF + (qb + 16 * j) * 272 + mm * 2);
        f16x8 zz = {};
        g0.v = __builtin_elementwise_max(kv0.v + qv.v, zz);
        g1.v = __builtin_elementwise_max(kv1.v + qv.v, zz);
        #pragma unroll
        for (int c = 0; c < 4; ++c) {
          acc[0][j] = __builtin_amdgcn_fdot2(g0.h[c], wv.h[c], acc[0][j], false);
          acc[1][j] = __builtin_amdgcn_fdot2(g1.h[c], wv.h[c], acc[1][j], false);
        }
      }
    }
    __syncthreads();
  }
#undef LOADW
  // ---- epilogue: sc + pmax ----
  #pragma unroll
  for (int i = 0; i < 2; ++i)
    #pragma unroll
    for (int j = 0; j < 4; ++j)
      sc[((size_t)b * L1 + qb + 16 * j) * LL + l0 + lq + 16 * i] = acc[i][j];
  #pragma unroll
  for (int j = 0; j < 4; ++j)
    *reinterpret_cast<f16*>(lds + SMAX_OFF + ((qb + 16 * j) * 18 + lq) * 2) =
        (f16)fmaxf(acc[0][j], acc[1][j]);
  __syncthreads();
  if (t < 64) {
    float m = -3.4e38f;
    #pragma unroll
    for (int i = 0; i < 16; ++i)
      m = fmaxf(m, (float)*reinterpret_cast<const f16*>(
                       lds + SMAX_OFF + (t * 18 + i) * 2));
    pmax[((size_t)b * L1 + t) * 32 + (l0 >> 5)] = m;
  }
}

// ---------------------------------------------------------------------------
// K3: fused softmax + PV GEMM, direct output.
// Grid 256 = 8 b x 32 d-tiles(16). Row-max from pmax.
// ---------------------------------------------------------------------------
__global__ __launch_bounds__(256) void fso_kernel(
    const float* __restrict__ sc,   // [8,64,1024] f32
    const float* __restrict__ pmax, // [8,64,32] f32
    const float* __restrict__ v,    // [8,1024,512] f32
    float* __restrict__ out) {      // [8,64,512] f32
  __shared__ __align__(16) char es[64 * 256];   // 16 KB, swizzled f16 rows
  __shared__ __align__(16) char vt[16 * 256];   // 4 KB, swizzled f16 rows
  __shared__ float rowm[64];
  __shared__ float rowinv[64];
  __shared__ float spart[64][17];
  const int t = threadIdx.x;
  const int lane = t & 63;
  const int w = t >> 6;
  const int fq = lane >> 4, fr = lane & 15;
  const int bid = blockIdx.x;
  const int b = bid & 7;
  const int d0 = (bid >> 3) * 16;
  const float* scb = sc + (size_t)b * L1 * LL;
  const float* vb = v + (size_t)b * LL * DD;

  const int eq = t >> 4;        // es row base (0..15), rows eq+16p
  const int ec8 = t & 15;       // es col8 (l = ec8*8 within chunk)
  const int vl = t >> 1;        // vt l (0..127)
  const int vdh = (t & 1) * 8;  // vt d half (0 or 8)
  float4 rsc[4][2];
  float4 rv[2];

#define LOADC(LC)                                                              \
  do {                                                                         \
    _Pragma("unroll") for (int p = 0; p < 4; ++p) {                            \
      const float* src = scb + (size_t)(eq + p * 16) * LL + (LC) * 128 + ec8 * 8; \
      rsc[p][0] = *reinterpret_cast<const float4*>(src);                       \
      rsc[p][1] = *reinterpret_cast<const float4*>(src + 4);                   \
    }                                                                          \
    const float* vsrc = vb + (size_t)((LC) * 128 + vl) * DD + d0 + vdh;        \
    rv[0] = *reinterpret_cast<const float4*>(vsrc);                            \
    rv[1] = *reinterpret_cast<const float4*>(vsrc + 4);                        \
  } while (0)

  LOADC(0);
  if (t < 64) {
    const float* pm = pmax + ((size_t)b * L1 + t) * 32;
    float4 m4 = *reinterpret_cast<const float4*>(pm);
    #pragma unroll
    for (int i = 1; i < 8; ++i) {
      float4 x = *reinterpret_cast<const float4*>(pm + i * 4);
      m4.x = fmaxf(m4.x, x.x); m4.y = fmaxf(m4.y, x.y);
      m4.z = fmaxf(m4.z, x.z); m4.w = fmaxf(m4.w, x.w);
    }
    rowm[t] = fmaxf(fmaxf(m4.x, m4.y), fmaxf(m4.z, m4.w));
  }
  __syncthreads();
  float rmv[4];
  #pragma unroll
  for (int p = 0; p < 4; ++p) rmv[p] = rowm[eq + p * 16];
  float spp[4] = {0.f, 0.f, 0.f, 0.f};
  f32x4 acc = {};

  for (int c = 0; c < 8; ++c) {
    #pragma unroll
    for (int p = 0; p < 4; ++p) {
      int q = eq + p * 16;
      float xs[8] = {rsc[p][0].x, rsc[p][0].y, rsc[p][0].z, rsc[p][0].w,
                     rsc[p][1].x, rsc[p][1].y, rsc[p][1].z, rsc[p][1].w};
      f16x8 h;
      #pragma unroll
      for (int j = 0; j < 8; ++j) {
        float e = __expf(xs[j] - rmv[p]);
        spp[p] += e;
        h[j] = (f16)e;
      }
      int byte = q * 256 + ((ec8 * 16) ^ ((q & 7) << 4));
      *reinterpret_cast<f16x8*>(es + byte) = h;
    }
    {
      float vs[8] = {rv[0].x, rv[0].y, rv[0].z, rv[0].w,
                     rv[1].x, rv[1].y, rv[1].z, rv[1].w};
      #pragma unroll
      for (int j = 0; j < 8; ++j) {
        int d = vdh + j;
        int byte = d * 256 + ((2 * vl) ^ ((d & 7) << 4));
        *reinterpret_cast<f16*>(vt + byte) = (f16)vs[j];
      }
    }
    if (c < 7) LOADC(c + 1);
    __syncthreads();
    #pragma unroll
    for (int ks = 0; ks < 4; ++ks) {
      int qa = w * 16 + fr;
      int colb = ks * 64 + fq * 16;
      f16x8 a = *reinterpret_cast<const f16x8*>(es + qa * 256 + (colb ^ ((qa & 7) << 4)));
      f16x8 bb = *reinterpret_cast<const f16x8*>(vt + fr * 256 + (colb ^ ((fr & 7) << 4)));
      acc = __builtin_amdgcn_mfma_f32_16x16x32_f16(a, bb, acc, 0, 0, 0);
    }
    __syncthreads();
  }
#undef LOADC
  #pragma unroll
  for (int p = 0; p < 4; ++p) spart[eq + p * 16][ec8] = spp[p];
  __syncthreads();
  if (t < 64) {
    float S = 0.f;
    #pragma unroll
    for (int i = 0; i < 16; ++i) S += spart[t][i];
    rowinv[t] = 1.f / S;
  }
  __syncthreads();
  #pragma unroll
  for (int r = 0; r < 4; ++r) {
    int q = w * 16 + fq * 4 + r;
    out[((size_t)b * L1 + q) * DD + d0 + fr] = acc[r] * rowinv[q];
  }
}

// ---------------------------------------------------------------------------
extern "C" void kernel_launch(void* const* d_in, const int* in_sizes, int n_in,
                              void* d_out, int out_size, void* d_ws, size_t ws_size,
                              hipStream_t stream) {
  const float* query  = (const float*)d_in[0];  // [64,512]
  const float* keys   = (const float*)d_in[1];  // [8,1024,512]
  const float* values = (const float*)d_in[2];  // [8,1024,512]
  const float* Wx     = (const float*)d_in[3];  // [512,512]
  const float* Wh     = (const float*)d_in[4];  // [512,512]
  const float* bh     = (const float*)d_in[5];  // [512]
  const float* w      = (const float*)d_in[6];  // [512]
  float* out = (float*)d_out;                   // [8,64,512]

  char* ws = (char*)d_ws;
  f16*   qh   = (f16*)ws;                  // 64 KB
  float* sc   = (float*)(ws + 65536);      // 2 MB
  float* pmax = (float*)(ws + 65536 + 2097152);  // 64 KB

  qh_kernel<<<8, 256, 0, stream>>>(query, Wh, bh, qh);
  kscore_kernel<<<256, 256, 0, stream>>>(keys, qh, Wx, w, sc, pmax);
  fso_kernel<<<256, 256, 0, stream>>>(sc, pmax, values, out);
}